// Round 11
// baseline (325.869 us; speedup 1.0000x reference)
//
#include <hip/hip_runtime.h>
#include <stdint.h>

#define BB   8
#define CC   256
#define HN   16384          // H*W
#define NV4  4096           // HN/4 (float4 / uint4 elements per row)
#define NFG  16
#define NBG  4
#define NQ   20             // NFG + NBG
#define NCHUNK 64           // N-chunks per batch in k_pack
#define CPB  4              // channels per k_sum block
#define SPLIT 4             // N-splits per (b, ctile)
#define CT   (CC / CPB)     // 64 channel tiles

// ---- workspace layout (all fully rewritten every call -> deterministic) ----
// [0, 524288)            uint32 word[B][HN]              packed 20 mask bits/pixel
// [524288, 565248)       int    cnt_part[64][B][NQ]      per-chunk counts
// [565248, 630784)       u64    amax_part[64][B][NFG]    per-chunk argmax keys
// [630784, 1286144)      float  part[B][NQ][CC][SPLIT]   split partial sums
// [1286144, 1288192)     int    ticket[B*CT]             arrival counters (zeroed by k_pack)
#define WS_WORD  0
#define WS_CNTP  524288
#define WS_AMAXP 565248
#define WS_PART  630784
#define WS_TICK  1286144

// =============== Kernel 1: bit-pack masks + per-block count/argmax partials ===============
__global__ __launch_bounds__(256) void k_pack(const float* __restrict__ fg,
                                              const float* __restrict__ bg,
                                              uint32_t* __restrict__ word,
                                              int* __restrict__ cnt_part,
                                              unsigned long long* __restrict__ amax_part,
                                              int* __restrict__ ticket) {
    __shared__ int                lcnt[NQ][4];
    __shared__ unsigned long long lmax[NFG][4];

    int bx    = blockIdx.x;
    int b     = bx >> 6;                     // 64 chunks per batch
    int chunk = bx & 63;
    int t     = threadIdx.x;
    int n     = (chunk << 8) + t;
    int lane  = t & 63;
    int wv    = t >> 6;                      // wave id 0..3

    if (t == 0) ticket[bx] = 0;              // zero arrival counters for k_sum (512 == grid)

    const float* fgb = fg + (size_t)b * NFG * HN + n;
    const float* bgb = bg + (size_t)b * NBG * HN + n;

    // issue ALL loads first (20 outstanding -> one latency exposure)
    float vf[NFG], vb[NBG];
    #pragma unroll
    for (int m = 0; m < NFG; ++m) vf[m] = fgb[(size_t)m * HN];
    #pragma unroll
    for (int j = 0; j < NBG; ++j) vb[j] = bgb[(size_t)j * HN];

    uint32_t w = 0;
    #pragma unroll
    for (int m = 0; m < NFG; ++m) {
        float v = vf[m];
        bool  p = v > 0.5f;
        if (p) w |= (1u << m);
        unsigned long long bal = __ballot(p);
        if (lane == 0) lcnt[m][wv] = (int)__popcll(bal);
        // value-only wave max, then first-lane-with-max via ballot+ffs
        float mv = v;
        #pragma unroll
        for (int off = 32; off >= 1; off >>= 1) mv = fmaxf(mv, __shfl_xor(mv, off));
        unsigned long long eq = __ballot(v == mv);
        if (lane == 0) {
            int fl = __ffsll(eq) - 1;                        // lowest lane == smallest n
            int mi = (chunk << 8) + (wv << 6) + fl;
            // non-negative floats: uint ordering == float ordering; ~idx -> smaller idx wins ties
            lmax[m][wv] = ((unsigned long long)__float_as_uint(mv) << 32) |
                          (unsigned long long)(0xFFFFFFFFu - (uint32_t)mi);
        }
    }
    #pragma unroll
    for (int j = 0; j < NBG; ++j) {
        bool p = vb[j] > 0.5f;
        if (p) w |= (1u << (NFG + j));
        unsigned long long bal = __ballot(p);
        if (lane == 0) lcnt[NFG + j][wv] = (int)__popcll(bal);
    }
    word[(size_t)b * HN + n] = w;

    __syncthreads();
    if (t < NQ) {
        int c = lcnt[t][0] + lcnt[t][1] + lcnt[t][2] + lcnt[t][3];
        cnt_part[((size_t)chunk * BB + b) * NQ + t] = c;
    }
    if (t < NFG) {
        unsigned long long k0 = lmax[t][0], k1 = lmax[t][1];
        unsigned long long k2 = lmax[t][2], k3 = lmax[t][3];
        unsigned long long k = k0 > k1 ? k0 : k1;
        unsigned long long l = k2 > k3 ? k2 : k3;
        amax_part[((size_t)chunk * BB + b) * NFG + t] = k > l ? k : l;
    }
}

// =============== Kernel 2: masked split-sums + fused finalize ===============
// block = (batch b, 4-channel tile ct, N-split s). 256 threads x 4 float4-iters.
// __launch_bounds__(256,4): cap VGPR at 128 -> 4 waves/SIMD (16/CU) to close the
// latency residual (r6-r10: ~3 waves/SIMD left BW at ~65%, VALU ~50%).
// Last-arriving split block per (b,ct) (ticket atomic) reduces the SPLIT
// partials + cnt/amax chunks and writes the output -> no k_fin launch.
__global__ __launch_bounds__(256, 4) void k_sum(const float* __restrict__ fmap,
                                                const uint32_t* __restrict__ word,
                                                const int* __restrict__ cnt_part,
                                                const unsigned long long* __restrict__ amax_part,
                                                float* __restrict__ part,
                                                int* __restrict__ ticket,
                                                float* __restrict__ out) {
    __shared__ float red[NQ][260];   // +4 pad, ~20.3 KiB
    __shared__ int   slast;

    int bx = blockIdx.x;             // ((b*CT)+ct)*SPLIT + s
    int s  = bx & (SPLIT - 1);
    int ct = (bx >> 2) & (CT - 1);
    int b  = bx >> 8;
    int t  = threadIdx.x;

    const uint4*  wp = (const uint4*)(word + (size_t)b * HN);
    const float4* f0 = (const float4*)(fmap + ((size_t)b * CC + ct * CPB) * HN);

    float acc[NQ][CPB];
    #pragma unroll
    for (int q = 0; q < NQ; ++q)
        #pragma unroll
        for (int r = 0; r < CPB; ++r) acc[q][r] = 0.f;

    for (int k = 0; k < 4; ++k) {
        int nx = (s << 10) + (k << 8) + t;
        uint4  w4 = wp[nx];
        float4 vv[CPB];
        #pragma unroll
        for (int r = 0; r < CPB; ++r) vv[r] = f0[r * NV4 + nx];

        const uint32_t wb[4] = {w4.x, w4.y, w4.z, w4.w};
        #pragma unroll
        for (int j = 0; j < 4; ++j) {
            uint32_t wrd = wb[j];
            #pragma unroll
            for (int q = 0; q < NQ; ++q) {
                float wq = (float)((wrd >> q) & 1u);
                #pragma unroll
                for (int r = 0; r < CPB; ++r)
                    acc[q][r] = fmaf(wq, ((const float*)&vv[r])[j], acc[q][r]);
            }
        }
    }

    // block reduction, one channel at a time; write split partials
    #pragma unroll
    for (int ch = 0; ch < CPB; ++ch) {
        __syncthreads();
        #pragma unroll
        for (int q = 0; q < NQ; ++q) red[q][t] = acc[q][ch];
        __syncthreads();
        // 256 -> 64
        for (int idx = t; idx < NQ * 64; idx += 256) {
            int q = idx >> 6, c = idx & 63;
            red[q][c] += red[q][c + 64] + red[q][c + 128] + red[q][c + 192];
        }
        __syncthreads();
        // 64 -> 8
        if (t < NQ * 8) {
            int q = t >> 3, c = t & 7;
            float v = red[q][c];
            #pragma unroll
            for (int j = 1; j < 8; ++j) v += red[q][c + 8 * j];
            red[q][c] = v;
        }
        __syncthreads();
        if (t < NQ) {
            float v = 0.f;
            #pragma unroll
            for (int j = 0; j < 8; ++j) v += red[t][j];
            part[(((size_t)b * NQ + t) * CC + (ct * CPB + ch)) * SPLIT + s] = v;
        }
    }

    // ---- arrival ticket: last split block for (b,ct) finalizes ----
    __syncthreads();
    if (t == 0) {
        __threadfence();                                   // release part writes
        slast = (atomicAdd(&ticket[(b * CT) + ct], 1) == SPLIT - 1);
    }
    __syncthreads();
    if (!slast) return;
    __threadfence();                                       // acquire other blocks' parts

    // finalize 80 outputs: thread t<80 -> (q = t/CPB? no: q-major) q = t>>2, ch = t&3
    if (t < NQ * CPB) {
        int q  = t >> 2;
        int ch = t & 3;
        int c  = ct * CPB + ch;

        int cq = 0;
        for (int k = 0; k < NCHUNK; ++k)
            cq += cnt_part[((size_t)k * BB + b) * NQ + q];

        const float* pp = part + (((size_t)b * NQ + q) * CC + c) * SPLIT;
        float sum = 0.f;
        #pragma unroll
        for (int j = 0; j < SPLIT; ++j) sum += pp[j];

        if (q < NFG) {
            float o;
            if (cq > 0) {
                o = sum / (float)cq;
            } else {
                unsigned long long key = 0ull;
                for (int k = 0; k < NCHUNK; ++k) {
                    unsigned long long kk = amax_part[((size_t)k * BB + b) * NFG + q];
                    key = kk > key ? kk : key;
                }
                int idxn = (int)(0xFFFFFFFFu - (uint32_t)key);
                o = fmap[((size_t)b * CC + c) * HN + idxn];
            }
            out[((size_t)b * NFG + q) * CC + c] = o;
        } else {
            out[(size_t)BB * NFG * CC + ((size_t)b * NBG + (q - NFG)) * CC + c] =
                (cq > 0) ? sum / (float)cq : 0.0f;
        }
    }
}

extern "C" void kernel_launch(void* const* d_in, const int* in_sizes, int n_in,
                              void* d_out, int out_size, void* d_ws, size_t ws_size,
                              hipStream_t stream) {
    const float* fmap = (const float*)d_in[0];   // [8][256][128][128] f32
    const float* fg   = (const float*)d_in[1];   // [8][16][128][128]  f32
    const float* bg   = (const float*)d_in[2];   // [8][4][128][128]   f32
    float* out = (float*)d_out;                  // fg[8][16][256] ++ bg[8][4][256]

    uint32_t*           word      = (uint32_t*)((char*)d_ws + WS_WORD);
    int*                cnt_part  = (int*)((char*)d_ws + WS_CNTP);
    unsigned long long* amax_part = (unsigned long long*)((char*)d_ws + WS_AMAXP);
    float*              part      = (float*)((char*)d_ws + WS_PART);
    int*                ticket    = (int*)((char*)d_ws + WS_TICK);

    k_pack<<<dim3(BB * NCHUNK), dim3(256), 0, stream>>>(fg, bg, word, cnt_part, amax_part, ticket);
    k_sum <<<dim3(BB * CT * SPLIT), dim3(256), 0, stream>>>(fmap, word, cnt_part, amax_part, part, ticket, out);
}

// Round 12
// 46.511 us; speedup vs baseline: 7.0063x; 7.0063x over previous
//
#include <hip/hip_runtime.h>
#include <stdint.h>

#define BB   8
#define CC   256
#define HN   16384          // H*W
#define NV4  4096           // HN/4 (float4 / uint4 elements per row)
#define NFG  16
#define NBG  4
#define NQ   20             // NFG + NBG
#define NCHUNK 64           // N-chunks per batch in k_pack
#define CPB  4              // channels per k_sum block
#define SPLIT 4             // N-splits per (b, ctile)
#define CT   (CC / CPB)     // 64 channel tiles

// ---- workspace layout (all fully rewritten every call -> deterministic) ----
// [0, 524288)            uint32 word[B][HN]              packed 20 mask bits/pixel
// [524288, 565248)       int    cnt_part[64][B][NQ]      per-chunk counts
// [565248, 630784)       u64    amax_part[64][B][NFG]    per-chunk argmax keys
// [630784, 1286144)      float  part[B][NQ][CC][SPLIT]   split partial sums
#define WS_WORD  0
#define WS_CNTP  524288
#define WS_AMAXP 565248
#define WS_PART  630784

// =============== Kernel 1: bit-pack masks + per-block count/argmax partials ===============
__global__ __launch_bounds__(256) void k_pack(const float* __restrict__ fg,
                                              const float* __restrict__ bg,
                                              uint32_t* __restrict__ word,
                                              int* __restrict__ cnt_part,
                                              unsigned long long* __restrict__ amax_part) {
    __shared__ int                lcnt[NQ][4];
    __shared__ unsigned long long lmax[NFG][4];

    int bx    = blockIdx.x;
    int b     = bx >> 6;                     // 64 chunks per batch
    int chunk = bx & 63;
    int t     = threadIdx.x;
    int n     = (chunk << 8) + t;
    int lane  = t & 63;
    int wv    = t >> 6;                      // wave id 0..3

    const float* fgb = fg + (size_t)b * NFG * HN + n;
    const float* bgb = bg + (size_t)b * NBG * HN + n;

    // issue ALL loads first (20 outstanding -> one latency exposure)
    float vf[NFG], vb[NBG];
    #pragma unroll
    for (int m = 0; m < NFG; ++m) vf[m] = fgb[(size_t)m * HN];
    #pragma unroll
    for (int j = 0; j < NBG; ++j) vb[j] = bgb[(size_t)j * HN];

    uint32_t w = 0;
    #pragma unroll
    for (int m = 0; m < NFG; ++m) {
        float v = vf[m];
        bool  p = v > 0.5f;
        if (p) w |= (1u << m);
        unsigned long long bal = __ballot(p);
        if (lane == 0) lcnt[m][wv] = (int)__popcll(bal);
        // value-only wave max, then first-lane-with-max via ballot+ffs
        float mv = v;
        #pragma unroll
        for (int off = 32; off >= 1; off >>= 1) mv = fmaxf(mv, __shfl_xor(mv, off));
        unsigned long long eq = __ballot(v == mv);
        if (lane == 0) {
            int fl = __ffsll(eq) - 1;                        // lowest lane == smallest n
            int mi = (chunk << 8) + (wv << 6) + fl;
            // non-negative floats: uint ordering == float ordering; ~idx -> smaller idx wins ties
            lmax[m][wv] = ((unsigned long long)__float_as_uint(mv) << 32) |
                          (unsigned long long)(0xFFFFFFFFu - (uint32_t)mi);
        }
    }
    #pragma unroll
    for (int j = 0; j < NBG; ++j) {
        bool p = vb[j] > 0.5f;
        if (p) w |= (1u << (NFG + j));
        unsigned long long bal = __ballot(p);
        if (lane == 0) lcnt[NFG + j][wv] = (int)__popcll(bal);
    }
    word[(size_t)b * HN + n] = w;

    __syncthreads();
    if (t < NQ) {
        int c = lcnt[t][0] + lcnt[t][1] + lcnt[t][2] + lcnt[t][3];
        cnt_part[((size_t)chunk * BB + b) * NQ + t] = c;
    }
    if (t < NFG) {
        unsigned long long k0 = lmax[t][0], k1 = lmax[t][1];
        unsigned long long k2 = lmax[t][2], k3 = lmax[t][3];
        unsigned long long k = k0 > k1 ? k0 : k1;
        unsigned long long l = k2 > k3 ? k2 : k3;
        amax_part[((size_t)chunk * BB + b) * NFG + t] = k > l ? k : l;
    }
}

// =============== Kernel 2: masked split-sums ===============
// block = (batch b, 4-channel tile ct, N-split s). 256 threads x 4 float4-iters.
// __launch_bounds__(256,2): empirical VGPR cap = 256/arg2 = 128 on this compiler
// (r11: arg2=4 -> 64 VGPR -> acc[80] spilled, 175MB scratch). 128 fits the
// ~110-120 live set (80 acc + loads + addressing) -> 4 waves/SIMD vs 3, which
// covers the ~900cyc HBM latency with the ~340cyc/iter VALU block.
__global__ __launch_bounds__(256, 2) void k_sum(const float* __restrict__ fmap,
                                                const uint32_t* __restrict__ word,
                                                float* __restrict__ part) {
    __shared__ float red[NQ][260];   // +4 pad, ~20.3 KiB

    int bx = blockIdx.x;             // ((b*CT)+ct)*SPLIT + s
    int s  = bx & (SPLIT - 1);
    int ct = (bx >> 2) & (CT - 1);
    int b  = bx >> 8;
    int t  = threadIdx.x;

    const uint4*  wp = (const uint4*)(word + (size_t)b * HN);
    const float4* f0 = (const float4*)(fmap + ((size_t)b * CC + ct * CPB) * HN);

    float acc[NQ][CPB];
    #pragma unroll
    for (int q = 0; q < NQ; ++q)
        #pragma unroll
        for (int r = 0; r < CPB; ++r) acc[q][r] = 0.f;

    for (int k = 0; k < 4; ++k) {
        int nx = (s << 10) + (k << 8) + t;
        uint4  w4 = wp[nx];
        float4 v0 = f0[nx];
        float4 v1 = f0[NV4 + nx];
        float4 v2 = f0[2 * NV4 + nx];
        float4 v3 = f0[3 * NV4 + nx];

        const uint32_t wb[4] = {w4.x, w4.y, w4.z, w4.w};
        #pragma unroll
        for (int j = 0; j < 4; ++j) {
            uint32_t wrd = wb[j];
            float a0 = ((const float*)&v0)[j];
            float a1 = ((const float*)&v1)[j];
            float a2 = ((const float*)&v2)[j];
            float a3 = ((const float*)&v3)[j];
            #pragma unroll
            for (int q = 0; q < NQ; ++q) {
                float wq = (float)((wrd >> q) & 1u);
                acc[q][0] = fmaf(wq, a0, acc[q][0]);
                acc[q][1] = fmaf(wq, a1, acc[q][1]);
                acc[q][2] = fmaf(wq, a2, acc[q][2]);
                acc[q][3] = fmaf(wq, a3, acc[q][3]);
            }
        }
    }

    // block reduction, one channel at a time; write split partials
    #pragma unroll
    for (int ch = 0; ch < CPB; ++ch) {
        __syncthreads();
        #pragma unroll
        for (int q = 0; q < NQ; ++q) red[q][t] = acc[q][ch];
        __syncthreads();
        // 256 -> 64
        for (int idx = t; idx < NQ * 64; idx += 256) {
            int q = idx >> 6, c = idx & 63;
            red[q][c] += red[q][c + 64] + red[q][c + 128] + red[q][c + 192];
        }
        __syncthreads();
        // 64 -> 8
        if (t < NQ * 8) {
            int q = t >> 3, c = t & 7;
            float v = red[q][c];
            #pragma unroll
            for (int j = 1; j < 8; ++j) v += red[q][c + 8 * j];
            red[q][c] = v;
        }
        __syncthreads();
        if (t < NQ) {
            float v = 0.f;
            #pragma unroll
            for (int j = 0; j < 8; ++j) v += red[t][j];
            part[(((size_t)b * NQ + t) * CC + (ct * CPB + ch)) * SPLIT + s] = v;
        }
    }
}

// =============== Kernel 3: finalize ===============
// block = (q, b); 256 threads = channels. Reduces SPLIT partials + 64 chunk
// cnt/amax partials, applies mean / argmax-fallback / bg-zero.
__global__ __launch_bounds__(256) void k_fin(const float* __restrict__ part,
                                             const int* __restrict__ cnt_part,
                                             const unsigned long long* __restrict__ amax_part,
                                             const float* __restrict__ fmap,
                                             float* __restrict__ out) {
    __shared__ int                scnt;
    __shared__ unsigned long long skey;

    int q = blockIdx.x;
    int b = blockIdx.y;
    int t = threadIdx.x;

    if (t < 64) {                       // wave 0: reduce counts over 64 chunks
        int cv = cnt_part[((size_t)t * BB + b) * NQ + q];
        #pragma unroll
        for (int off = 32; off >= 1; off >>= 1) cv += __shfl_xor(cv, off);
        if (t == 0) scnt = cv;
    } else if (t < 128 && q < NFG) {    // wave 1: reduce argmax keys
        unsigned long long k = amax_part[((size_t)(t - 64) * BB + b) * NFG + q];
        #pragma unroll
        for (int off = 32; off >= 1; off >>= 1) {
            unsigned long long o = __shfl_xor(k, off);
            k = o > k ? o : k;
        }
        if (t == 64) skey = k;
    }
    __syncthreads();

    int cq = scnt;
    float4 p4 = ((const float4*)part)[((size_t)b * NQ + q) * CC + t];
    float  s  = (p4.x + p4.y) + (p4.z + p4.w);

    if (q < NFG) {
        float o;
        if (cq > 0) {
            o = s / (float)cq;
        } else {
            int idxn = (int)(0xFFFFFFFFu - (uint32_t)skey);
            o = fmap[((size_t)b * CC + t) * HN + idxn];
        }
        out[((size_t)b * NFG + q) * CC + t] = o;
    } else {
        out[(size_t)BB * NFG * CC + ((size_t)b * NBG + (q - NFG)) * CC + t] =
            (cq > 0) ? s / (float)cq : 0.0f;
    }
}

extern "C" void kernel_launch(void* const* d_in, const int* in_sizes, int n_in,
                              void* d_out, int out_size, void* d_ws, size_t ws_size,
                              hipStream_t stream) {
    const float* fmap = (const float*)d_in[0];   // [8][256][128][128] f32
    const float* fg   = (const float*)d_in[1];   // [8][16][128][128]  f32
    const float* bg   = (const float*)d_in[2];   // [8][4][128][128]   f32
    float* out = (float*)d_out;                  // fg[8][16][256] ++ bg[8][4][256]

    uint32_t*           word      = (uint32_t*)((char*)d_ws + WS_WORD);
    int*                cnt_part  = (int*)((char*)d_ws + WS_CNTP);
    unsigned long long* amax_part = (unsigned long long*)((char*)d_ws + WS_AMAXP);
    float*              part      = (float*)((char*)d_ws + WS_PART);

    k_pack<<<dim3(BB * NCHUNK), dim3(256), 0, stream>>>(fg, bg, word, cnt_part, amax_part);
    k_sum <<<dim3(BB * CT * SPLIT), dim3(256), 0, stream>>>(fmap, word, part);
    k_fin <<<dim3(NQ, BB), dim3(256), 0, stream>>>(part, cnt_part, amax_part, fmap, out);
}